// Round 3
// baseline (369.242 us; speedup 1.0000x reference)
//
#include <hip/hip_runtime.h>

#define NN 50000
#define NE 800000
#define EH (NE + NN)   // 850000 edges incl. self-loops
#define HD 128
#define NB 196         // ceil(NN/256)
#define NCH 8          // column chunks (one per XCD)
#define CPW 16         // cols per chunk
#define PSTR (NN * CPW)  // floats per panel = 800000

// ---------------- degree / CSR build ----------------
__global__ void k_init_deg(int* __restrict__ deg) {
  int i = blockIdx.x * 256 + threadIdx.x;
  if (i < NN) deg[i] = 1;   // self-loop contributes 1
}

__global__ void k_count(const int* __restrict__ dst, int* __restrict__ deg) {
  int e = blockIdx.x * 256 + threadIdx.x;
  if (e < NE) atomicAdd(&deg[dst[e]], 1);
}

// stage 1: per-block sums of deg
__global__ __launch_bounds__(256) void k_partial(const int* __restrict__ deg,
                                                 int* __restrict__ partial) {
  int i = blockIdx.x * 256 + threadIdx.x;
  int v = (i < NN) ? deg[i] : 0;
  #pragma unroll
  for (int off = 32; off >= 1; off >>= 1) v += __shfl_down(v, off);
  __shared__ int ws[4];
  if ((threadIdx.x & 63) == 0) ws[threadIdx.x >> 6] = v;
  __syncthreads();
  if (threadIdx.x == 0) partial[blockIdx.x] = ws[0] + ws[1] + ws[2] + ws[3];
}

// stage 2: exclusive scan of the 196 partials (single small block)
__global__ __launch_bounds__(256) void k_scanp(int* __restrict__ partial) {
  __shared__ int lds[256];
  int t = threadIdx.x;
  int v = (t < NB) ? partial[t] : 0;
  lds[t] = v;
  __syncthreads();
  #pragma unroll
  for (int off = 1; off < 256; off <<= 1) {
    int u = (t >= off) ? lds[t - off] : 0;
    __syncthreads();
    lds[t] += u;
    __syncthreads();
  }
  if (t < NB) partial[t] = lds[t] - v;   // exclusive
}

// stage 3: in-block exclusive scan + block offset -> row_start/cursor; fused dis=rsqrt(deg)
__global__ __launch_bounds__(256) void k_scatter(const int* __restrict__ deg,
                                                 const int* __restrict__ partial,
                                                 int* __restrict__ row_start,
                                                 int* __restrict__ cursor,
                                                 float* __restrict__ dis) {
  __shared__ int lds[256];
  int t = threadIdx.x;
  int i = blockIdx.x * 256 + t;
  int v = (i < NN) ? deg[i] : 0;
  lds[t] = v;
  __syncthreads();
  #pragma unroll
  for (int off = 1; off < 256; off <<= 1) {
    int u = (t >= off) ? lds[t - off] : 0;
    __syncthreads();
    lds[t] += u;
    __syncthreads();
  }
  int ex = lds[t] - v + partial[blockIdx.x];
  if (i < NN) {
    row_start[i] = ex;
    cursor[i] = ex;
    dis[i] = rsqrtf((float)v);   // deg >= 1 always
    if (i == NN - 1) row_start[NN] = ex + v;
  }
}

__global__ void k_fill(const int* __restrict__ src, const int* __restrict__ dst,
                       int* __restrict__ cursor, int* __restrict__ csr_src) {
  int e = blockIdx.x * 256 + threadIdx.x;
  if (e >= EH) return;
  int s, d;
  if (e < NE) { s = src[e]; d = dst[e]; }
  else        { s = e - NE; d = s; }          // self-loop
  int pos = atomicAdd(&cursor[d], 1);
  csr_src[pos] = s;
}

// ---------------- dense GEMM: C = A[NN,128] @ W[128,128], C in chunk-panel layout ----
// panel p (p=0..7) holds cols [16p,16p+16) of all rows, contiguous 3.2 MB each.
#define GR 128
__global__ __launch_bounds__(256, 1) void k_gemm(const float* __restrict__ A,
                                                 const float* __restrict__ W,
                                                 float* __restrict__ C) {
  __shared__ float As[GR][HD + 4];
  __shared__ float Ws[HD * HD];
  const int tid = threadIdx.x;
  const int r0 = blockIdx.x * GR;
  #pragma unroll
  for (int m = 0; m < 16; ++m) {
    int f = tid + m * 256;
    ((float4*)Ws)[f] = ((const float4*)W)[f];
  }
  #pragma unroll
  for (int m = 0; m < 16; ++m) {
    int f = tid + m * 256;
    int r = f >> 5, c4 = f & 31;
    int gr_ = r0 + r;
    float4 v = make_float4(0.f, 0.f, 0.f, 0.f);
    if (gr_ < NN) v = ((const float4*)A)[gr_ * 32 + c4];
    *(float4*)&As[r][c4 * 4] = v;
  }
  __syncthreads();
  const int tg = tid >> 4;
  const int tc = tid & 15;
  const int cc = tc * 4;
  float acc[8][8];
  #pragma unroll
  for (int j = 0; j < 8; ++j)
    #pragma unroll
    for (int c = 0; c < 8; ++c) acc[j][c] = 0.f;

  for (int k = 0; k < HD; k += 4) {
    float4 a[8];
    #pragma unroll
    for (int j = 0; j < 8; ++j) a[j] = *(const float4*)&As[tg + 16 * j][k];
    #pragma unroll
    for (int kk = 0; kk < 4; ++kk) {
      float4 w0 = *(const float4*)&Ws[(k + kk) * HD + cc];
      float4 w1 = *(const float4*)&Ws[(k + kk) * HD + cc + 64];
      #pragma unroll
      for (int j = 0; j < 8; ++j) {
        float av = (kk == 0) ? a[j].x : (kk == 1) ? a[j].y : (kk == 2) ? a[j].z : a[j].w;
        acc[j][0] += av * w0.x; acc[j][1] += av * w0.y;
        acc[j][2] += av * w0.z; acc[j][3] += av * w0.w;
        acc[j][4] += av * w1.x; acc[j][5] += av * w1.y;
        acc[j][6] += av * w1.z; acc[j][7] += av * w1.w;
      }
    }
  }
  const int p0 = cc >> 4;          // panel for cols cc..cc+3
  const int pc = cc & 15;          // col offset within panel (16B aligned)
  #pragma unroll
  for (int j = 0; j < 8; ++j) {
    int row = r0 + tg + 16 * j;
    if (row < NN) {
      *(float4*)&C[p0 * PSTR + row * CPW + pc]       = make_float4(acc[j][0], acc[j][1], acc[j][2], acc[j][3]);
      *(float4*)&C[(p0 + 4) * PSTR + row * CPW + pc] = make_float4(acc[j][4], acc[j][5], acc[j][6], acc[j][7]);
    }
  }
}

// ---------------- CSR gather-aggregate + bias + LeakyReLU (chunk-panel input) ------
// chunk = blockIdx % 8 -> XCD-steered: each XCD's gathers hit one 3.2 MB panel.
// block = 16 nodes x 16 cols.
__global__ __launch_bounds__(256) void k_agg(const float* __restrict__ Tpanels,
                                             const float* __restrict__ dis,
                                             const int* __restrict__ row_start,
                                             const int* __restrict__ csr_src,
                                             const float* __restrict__ bias,
                                             float* __restrict__ out) {
  const int tid = threadIdx.x;
  const int chunk = blockIdx.x & (NCH - 1);
  const int ng = blockIdx.x >> 3;
  const int n = ng * 16 + (tid >> 4);
  const int col = tid & 15;
  if (n >= NN) return;
  const float* __restrict__ P = Tpanels + chunk * PSTR;
  const int rs = row_start[n], re = row_start[n + 1];
  float acc = 0.f;
  int j = rs;
  for (; j + 3 < re; j += 4) {
    int s0 = csr_src[j], s1 = csr_src[j + 1], s2 = csr_src[j + 2], s3 = csr_src[j + 3];
    float w0 = dis[s0], w1 = dis[s1], w2 = dis[s2], w3 = dis[s3];
    float t0 = P[s0 * CPW + col];
    float t1 = P[s1 * CPW + col];
    float t2 = P[s2 * CPW + col];
    float t3 = P[s3 * CPW + col];
    acc += w0 * t0; acc += w1 * t1; acc += w2 * t2; acc += w3 * t3;
  }
  for (; j < re; ++j) {
    int s = csr_src[j];
    acc += dis[s] * P[s * CPW + col];
  }
  float v = acc * dis[n] + bias[chunk * CPW + col];
  out[n * HD + chunk * CPW + col] = (v >= 0.f) ? v : 0.01f * v;
}

extern "C" void kernel_launch(void* const* d_in, const int* in_sizes, int n_in,
                              void* d_out, int out_size, void* d_ws, size_t ws_size,
                              hipStream_t stream) {
  const float* x  = (const float*)d_in[0];
  const int*   ei = (const int*)d_in[1];
  const float* W0 = (const float*)d_in[2];
  const float* b0 = (const float*)d_in[3];
  const float* W1 = (const float*)d_in[4];
  const float* b1 = (const float*)d_in[5];
  float* out = (float*)d_out;
  const int* src = ei;        // edge_index[0] = message source
  const int* dst = ei + NE;   // edge_index[1] = aggregation target

  char* p = (char*)d_ws;
  int*   deg       = (int*)p;    p += 50048 * 4;
  float* dis       = (float*)p;  p += 50048 * 4;
  int*   row_start = (int*)p;    p += 50052 * 4;
  int*   cursor    = (int*)p;    p += 50048 * 4;
  int*   partial   = (int*)p;    p += 256 * 4;
  int*   csr       = (int*)p;    p += 850048 * 4;
  float* bufA      = (float*)p;  // 6,400,000 floats (25.6 MB) in 8 panels

  // graph build (once, reused by both layers)
  k_init_deg<<<196, 256, 0, stream>>>(deg);
  k_count<<<3125, 256, 0, stream>>>(dst, deg);
  k_partial<<<NB, 256, 0, stream>>>(deg, partial);
  k_scanp<<<1, 256, 0, stream>>>(partial);
  k_scatter<<<NB, 256, 0, stream>>>(deg, partial, row_start, cursor, dis);
  k_fill<<<(EH + 255) / 256, 256, 0, stream>>>(src, dst, cursor, csr);

  const int AGG_GRID = NCH * ((NN + 15) / 16);   // 8 * 3125 = 25000
  // layer 1
  k_gemm<<<(NN + GR - 1) / GR, 256, 0, stream>>>(x, W0, bufA);
  k_agg<<<AGG_GRID, 256, 0, stream>>>(bufA, dis, row_start, csr, b0, out);
  // layer 2
  k_gemm<<<(NN + GR - 1) / GR, 256, 0, stream>>>(out, W1, bufA);
  k_agg<<<AGG_GRID, 256, 0, stream>>>(bufA, dis, row_start, csr, b1, out);
}